// Round 7
// baseline (457.432 us; speedup 1.0000x reference)
//
#include <hip/hip_runtime.h>
#include <stdint.h>

#define D_DIM 1024
#define M_DIM 128
#define BR 32
#define BD 32
#define NCHUNK (D_DIM / BD)   // 32

// Bit-exact semantics (verified R7, absmax=0.0):
//   h[r][m]  = sequential __fmaf_rn chain over d = 0..1023 (ascending)
//   FWHT stages on column-bit 0,1,...,6 ascending; out[bit]=a+b / a-b, fp32
//   bit = (h > 0) ? 1.0f : 0.0f
//
// R14: lane = COLUMN. Wave tile = 128 cols x 8 rows; thread holds cols
// {lane, lane+64} x 8 rows (16 acc). X is then WAVE-UNIFORM -> s_load
// into SGPRs (scalar pipe); v_fma takes the SGPR as src0. X costs zero
// LDS/VMEM/VALU cycles. Per jp per wave: 2 ds_read_b128 (W) + 128 FMA
// cycles -> LDS:FMA = 0.75 per CU at 16 waves/CU: FMA-bound AND
// 4 waves/SIMD TLP (R8-R13 showed you can't get both with per-lane X).
//   - 256-thr blocks (4 waves x 8 rows = BR=32), grid 1024 = 4 blk/CU.
//   - W LDS dbuf 2x16KB via global_load_lds; chunk swizzle
//     physcj = cj ^ (col&7) via pre-swizzled GLOBAL source (linear DMA
//     dest), re-applied on read -> all 32 banks hit, standard b128 cost.
//   - FWHT: col bits 0..5 = lane (shfl_xor h=1..32, FIRST), bit 6 = ci
//     (register butterfly, LAST). Ascending bits preserved.
//   - plain launch_bounds(256): natural VGPR ~50-60 < 64 target, no
//     spill (session rule: min-occupancy hints >=4 force 64-reg spill).

typedef const __attribute__((address_space(1))) void* gas_cptr;
typedef __attribute__((address_space(3))) void* lds_vptr;

__device__ __forceinline__ void gload_lds16(const float* g, float* l) {
    __builtin_amdgcn_global_load_lds((gas_cptr)g, (lds_vptr)l, 16, 0, 0);
}

__global__ __launch_bounds__(256)
void rewa_kernel(const float* __restrict__ X, const float* __restrict__ W,
                 float* __restrict__ out) {
    #pragma clang fp contract(off)
    __shared__ float wsh[2][M_DIM * BD];   // 2 x 16 KB, chunk-swizzled

    const int t    = threadIdx.x;
    const int lane = t & 63;
    const int wv   = __builtin_amdgcn_readfirstlane(t >> 6);   // 0..3, SGPR
    const size_t row0 = (size_t)blockIdx.x * BR;

    // W staging: stripe s covers cols 8s..8s+7 (1 KB). Lane l writes LDS
    // at s*1024B + 16B*l => col 8s+(l>>3), phys chunk l&7; logical chunk
    // cj = (l&7) ^ (col&7) = (l&7) ^ ((l>>3)&7). Wave w stages 4q+w.
    const float* wsrc[4];
    int ldst[4];
    {
        const int cj = (lane & 7) ^ ((lane >> 3) & 7);
        #pragma unroll
        for (int q = 0; q < 4; ++q) {
            const int stripe = 4 * q + wv;              // 0..15
            const int col    = 8 * stripe + (lane >> 3);
            wsrc[q] = W + (size_t)col * D_DIM + 4 * cj;
            ldst[q] = stripe * 256;    // float offset of this 1 KB stripe
        }
    }

    // Uniform X row pointers for this wave's 8 rows (SGPR-held).
    const float* xu[8];
    #pragma unroll
    for (int rr = 0; rr < 8; ++rr)
        xu[rr] = X + (row0 + 8 * wv + rr) * D_DIM;

    float acc[2][8];   // [ci][rr], col = 64*ci + lane
    #pragma unroll
    for (int ci = 0; ci < 2; ++ci)
        #pragma unroll
        for (int rr = 0; rr < 8; ++rr) acc[ci][rr] = 0.0f;

    // prologue: stage chunk 0 into buffer 0
    #pragma unroll
    for (int q = 0; q < 4; ++q)
        gload_lds16(wsrc[q], &wsh[0][ldst[q]]);

    // Per-lane W read offsets (floats): row = 64ci+lane, physcj = jp^(lane&7)
    const int wr0 = lane * BD;            // ci=0 row base
    const int wr1 = (64 + lane) * BD;     // ci=1 row base
    const int swz = lane & 7;

    for (int ch = 0; ch < NCHUNK; ++ch) {
        __syncthreads();           // stage(ch) landed; prev buf reads done
        const int buf = ch & 1;
        const float* wb = &wsh[buf][0];

        if (ch + 1 < NCHUNK) {     // stage next chunk into other buffer
            const int d0n = (ch + 1) * BD;
            #pragma unroll
            for (int q = 0; q < 4; ++q)
                gload_lds16(wsrc[q] + d0n, &wsh[buf ^ 1][ldst[q]]);
        }

        const int d0 = ch * BD;
        #pragma unroll
        for (int jp = 0; jp < 8; ++jp) {
            // X: wave-uniform float4 per row -> s_load_dwordx4 (SGPRs)
            float4 xv[8];
            #pragma unroll
            for (int rr = 0; rr < 8; ++rr)
                xv[rr] = *(const float4*)(xu[rr] + d0 + 4 * jp);
            // W: one b128 per col-group
            float4 wf[2];
            wf[0] = *(const float4*)&wb[wr0 + ((jp ^ swz) << 2)];
            wf[1] = *(const float4*)&wb[wr1 + ((jp ^ swz) << 2)];
            // d = ch*32 + jp*4 + e, ascending (bit-exact chain order)
            #pragma unroll
            for (int e = 0; e < 4; ++e)
                #pragma unroll
                for (int rr = 0; rr < 8; ++rr) {
                    const float xe = ((const float*)&xv[rr])[e];
                    acc[0][rr] = __fmaf_rn(xe, ((const float*)&wf[0])[e],
                                           acc[0][rr]);
                    acc[1][rr] = __fmaf_rn(xe, ((const float*)&wf[1])[e],
                                           acc[1][rr]);
                }
        }
    }

    // ---- FWHT, fp32, ascending column bits. col = 64*ci + lane ----
    // bits 0..5 live in lane (shfl_xor, FIRST; rows are wave-uniform so
    // both shuffle ends hold the same rows)
    #pragma unroll
    for (int h = 1; h <= 32; h <<= 1) {
        const bool up = (lane & h) != 0;
        #pragma unroll
        for (int ci = 0; ci < 2; ++ci)
            #pragma unroll
            for (int rr = 0; rr < 8; ++rr) {
                const float mine  = acc[ci][rr];
                const float other = __shfl_xor(mine, h, 64);
                acc[ci][rr] = up ? __fsub_rn(other, mine)
                                 : __fadd_rn(mine, other);
            }
    }
    // bit 6 lives in ci (register butterfly, LAST)
    #pragma unroll
    for (int rr = 0; rr < 8; ++rr) {
        const float a = acc[0][rr], b = acc[1][rr];
        acc[0][rr] = __fadd_rn(a, b);
        acc[1][rr] = __fsub_rn(a, b);
    }

    // sign + coalesced dword stores (lane-consecutive cols)
    #pragma unroll
    for (int rr = 0; rr < 8; ++rr) {
        const size_t row = row0 + 8 * wv + rr;
        out[row * M_DIM + lane]      = (acc[0][rr] > 0.0f) ? 1.0f : 0.0f;
        out[row * M_DIM + lane + 64] = (acc[1][rr] > 0.0f) ? 1.0f : 0.0f;
    }
}

extern "C" void kernel_launch(void* const* d_in, const int* in_sizes, int n_in,
                              void* d_out, int out_size, void* d_ws, size_t ws_size,
                              hipStream_t stream) {
    const float* x = (const float*)d_in[0];
    const float* W = (const float*)d_in[1];
    float* out = (float*)d_out;
    const int nrows = out_size / M_DIM;   // 32768

    hipLaunchKernelGGL(rewa_kernel, dim3(nrows / BR), dim3(256), 0, stream,
                       x, W, out);
}

// Round 8
// 375.681 us; speedup vs baseline: 1.2176x; 1.2176x over previous
//
#include <hip/hip_runtime.h>
#include <stdint.h>

#define D_DIM 1024
#define M_DIM 128
#define BR 32
#define BD 32
#define NCHUNK (D_DIM / BD)   // 32

// Bit-exact semantics (verified R7, absmax=0.0):
//   h[r][m]  = sequential __fmaf_rn chain over d = 0..1023 (ascending)
//   FWHT stages on column-bit 0,1,...,6 ascending; out[bit]=a+b / a-b, fp32
//   bit = (h > 0) ? 1.0f : 0.0f
//
// R15: lane=col (R14 shape: wave = 128 cols x 8 rows) with three fixes.
//  * vmcnt collision fix (explains R10/R13/R14): s_waitcnt vmcnt(N)
//    retires OLDEST first, so compute-phase X loads were draining the
//    in-flight next-chunk staging every jp. Now W staging is SINGLE-
//    buffered: stage -> barrier -> compute (X = only VMEM in flight)
//    -> barrier -> stage next. Staging stall amortized over 4 blk/CU.
//  * W LDS layout transposed: slot(row,cj) = row + 128*cj (16B slots).
//    Read = lane-consecutive 16B (canonical conflict-free b128). DMA
//    dest linear; transpose folded into per-lane GLOBAL source (16KB
//    L1-hot gather, staging-phase only).
//  * X prefetch depth-1, named ping-pong (compile-time parity).
// Per jp per wave: 2 ds_read_b128 + 8 uniform X loads + 64 FMA instrs.
// 16 waves/CU: VALU 512 cyc/SIMD-window > LDS 384 > TA ~130: FMA-bound.

typedef const __attribute__((address_space(1))) void* gas_cptr;
typedef __attribute__((address_space(3))) void* lds_vptr;
typedef float v4f __attribute__((ext_vector_type(4)));

__device__ __forceinline__ void gload_lds16(const float* g, float* l) {
    __builtin_amdgcn_global_load_lds((gas_cptr)g, (lds_vptr)l, 16, 0, 0);
}

__global__ __launch_bounds__(256, 1)
void rewa_kernel(const float* __restrict__ X, const float* __restrict__ W,
                 float* __restrict__ out) {
    #pragma clang fp contract(off)
    __shared__ float wsh[M_DIM * BD];   // 16 KB single buffer, [cj][row] slots

    const int t    = threadIdx.x;
    const int lane = t & 63;
    const int wv   = __builtin_amdgcn_readfirstlane(t >> 6);   // 0..3
    const size_t row0 = (size_t)blockIdx.x * BR;

    // Staging: instr stripe = 4q+wv writes LDS slots 64*stripe + lane.
    // slot = row + 128*cj  =>  row = 64*(stripe&1)+lane, cj = stripe>>1.
    // Global source pre-applies this transpose (16B gather, L1-hot).
    const float* wsrc[4];
    int ldst[4];
    #pragma unroll
    for (int q = 0; q < 4; ++q) {
        const int stripe = 4 * q + wv;              // 0..15
        const int srow   = 64 * (stripe & 1) + lane;
        const int cj     = stripe >> 1;
        wsrc[q] = W + (size_t)srow * D_DIM + 4 * cj;
        ldst[q] = stripe * 256;    // float offset of this 1 KB stripe
    }

    // Uniform X row pointers for this wave's 8 rows.
    const float* xu[8];
    #pragma unroll
    for (int rr = 0; rr < 8; ++rr)
        xu[rr] = X + (row0 + 8 * wv + rr) * D_DIM;

    float acc[2][8];   // [ci][rr], col = 64*ci + lane
    #pragma unroll
    for (int ci = 0; ci < 2; ++ci)
        #pragma unroll
        for (int rr = 0; rr < 8; ++rr) acc[ci][rr] = 0.0f;

    // prologue: stage chunk 0; prefetch X jp0 into xva
    #pragma unroll
    for (int q = 0; q < 4; ++q) {
        gload_lds16(wsrc[q], &wsh[ldst[q]]);
        wsrc[q] += BD;
    }
    v4f xva[8], xvb[8];
    #pragma unroll
    for (int rr = 0; rr < 8; ++rr)
        xva[rr] = *(const v4f*)(xu[rr]);

    const int wread0 = 4 * lane;   // + 256*ci + 512*jp (bytes: 16*lane)

    for (int ch = 0; ch < NCHUNK; ++ch) {
        __syncthreads();           // staging(ch) + prefetch landed
        const int d0 = ch * BD;

        #pragma unroll
        for (int jp = 0; jp < 8; ++jp) {
            // W fragments: lane-consecutive 16B -> conflict-free
            const v4f wf0 = *(const v4f*)&wsh[wread0 + 512 * jp];
            const v4f wf1 = *(const v4f*)&wsh[wread0 + 256 + 512 * jp];
            // X prefetch depth-1 (next jp, or next chunk's jp0)
            const int doff = (jp < 7) ? d0 + 4 * (jp + 1)
                           : ((ch + 1 < NCHUNK) ? d0 + BD : d0);  // tail: harmless refetch
            v4f* pf = (jp & 1) ? xva : xvb;           // compile-time (unrolled)
            #pragma unroll
            for (int rr = 0; rr < 8; ++rr)
                pf[rr] = *(const v4f*)(xu[rr] + doff);
            const v4f* cur = (jp & 1) ? xvb : xva;    // compile-time
            // d = ch*32 + jp*4 + e, ascending (bit-exact chain order)
            #pragma unroll
            for (int e = 0; e < 4; ++e)
                #pragma unroll
                for (int rr = 0; rr < 8; ++rr) {
                    const float xe = cur[rr][e];
                    acc[0][rr] = __fmaf_rn(xe, wf0[e], acc[0][rr]);
                    acc[1][rr] = __fmaf_rn(xe, wf1[e], acc[1][rr]);
                }
        }

        __syncthreads();           // all waves done reading wsh
        if (ch + 1 < NCHUNK) {     // stage next chunk (drained at loop-top)
            #pragma unroll
            for (int q = 0; q < 4; ++q) {
                gload_lds16(wsrc[q], &wsh[ldst[q]]);
                wsrc[q] += BD;
            }
        }
    }

    // ---- FWHT, fp32, ascending column bits. col = 64*ci + lane ----
    // bits 0..5 live in lane (shfl_xor, FIRST; rows are wave-uniform so
    // both shuffle ends hold the same rows)
    #pragma unroll
    for (int h = 1; h <= 32; h <<= 1) {
        const bool up = (lane & h) != 0;
        #pragma unroll
        for (int ci = 0; ci < 2; ++ci)
            #pragma unroll
            for (int rr = 0; rr < 8; ++rr) {
                const float mine  = acc[ci][rr];
                const float other = __shfl_xor(mine, h, 64);
                acc[ci][rr] = up ? __fsub_rn(other, mine)
                                 : __fadd_rn(mine, other);
            }
    }
    // bit 6 lives in ci (register butterfly, LAST)
    #pragma unroll
    for (int rr = 0; rr < 8; ++rr) {
        const float a = acc[0][rr], b = acc[1][rr];
        acc[0][rr] = __fadd_rn(a, b);
        acc[1][rr] = __fsub_rn(a, b);
    }

    // sign + coalesced dword stores (lane-consecutive cols)
    #pragma unroll
    for (int rr = 0; rr < 8; ++rr) {
        const size_t row = row0 + 8 * wv + rr;
        out[row * M_DIM + lane]      = (acc[0][rr] > 0.0f) ? 1.0f : 0.0f;
        out[row * M_DIM + lane + 64] = (acc[1][rr] > 0.0f) ? 1.0f : 0.0f;
    }
}

extern "C" void kernel_launch(void* const* d_in, const int* in_sizes, int n_in,
                              void* d_out, int out_size, void* d_ws, size_t ws_size,
                              hipStream_t stream) {
    const float* x = (const float*)d_in[0];
    const float* W = (const float*)d_in[1];
    float* out = (float*)d_out;
    const int nrows = out_size / M_DIM;   // 32768

    hipLaunchKernelGGL(rewa_kernel, dim3(nrows / BR), dim3(256), 0, stream,
                       x, W, out);
}